// Round 4
// baseline (17.118 us; speedup 1.0000x reference)
//
#include <hip/hip_runtime.h>
#include <hip/hip_bf16.h>

// B=512, N=64, D=128, 4 edge types.
// out[b] = softmax_j(select_k(leakyrelu((h*a_k) @ h^T), adj)) @ h

#define NB 512
#define NN 64
#define ND 128
#define HS 136   // h_lds row stride (128 + 8 pad)
#define AS 72    // alpha row stride
#define AJS 65   // adj_lds row stride (ints): staging writes conflict-free

typedef __bf16 bf16x8 __attribute__((ext_vector_type(8)));
typedef __bf16 bf16x4 __attribute__((ext_vector_type(4)));
typedef float  f32x4  __attribute__((ext_vector_type(4)));

__global__ __launch_bounds__(256)
void gat_kernel(const float* __restrict__ hidden,
                const int*   __restrict__ adj,
                const float* __restrict__ a,
                float*       __restrict__ out)
{
    __shared__ __bf16 h_lds[NN * HS];       // 17408 B  row-major, padded
    __shared__ __bf16 h_tr[8 * NN * 16];    // 16384 B  [dt][j][dcol] subtiled for tr-read
    __shared__ __bf16 al_lds[NN * AS];      //  9216 B  normalized alpha (bf16)
    __shared__ float  a_lds[4 * ND];        //  2048 B
    __shared__ int    adj_lds[NN * AJS];    // 16640 B
                                            //  total 61696 B -> 2 blocks/CU

    const int t = threadIdx.x;
    const int l = t & 63;
    const int w = t >> 6;
    const int b = blockIdx.x;
    const int g  = l >> 4;              // 16-lane group 0..3
    const int g8 = g << 3;
    const int i0 = w * 16 + (g << 2);   // e-GEMM C/D row base

    // ---- stage hidden[b]: f32 -> bf16 h_lds (row-major) + h_tr (subtiled) ----
    const float4* hin = (const float4*)(hidden + (size_t)b * NN * ND);
    #pragma unroll
    for (int it = 0; it < 8; ++it) {
        int row = ((l >> 2) & 15) | ((it >> 1) << 4);
        int f4  = (l & 3) | (w << 2) | ((it & 1) << 4);
        float4 v = hin[row * 32 + f4];
        bf16x4 pk = { (__bf16)v.x, (__bf16)v.y, (__bf16)v.z, (__bf16)v.w };
        int c4 = f4 << 2;
        *(bf16x4*)&h_lds[row * HS + c4] = pk;
        *(bf16x4*)&h_tr[((c4 >> 4) << 10) + (row << 4) + (c4 & 15)] = pk;
    }
    // ---- stage adj[b] (coalesced int4) -> adj_lds ----
    const int4* adjin = (const int4*)(adj + (size_t)b * NN * NN);
    #pragma unroll
    for (int it = 0; it < 4; ++it) {
        int idx = it * 256 + t;          // 1024 int4 total
        int4 v = adjin[idx];
        int ri = idx >> 4;
        int c4 = (idx & 15) << 2;
        int* p = &adj_lds[ri * AJS + c4];
        p[0] = v.x; p[1] = v.y; p[2] = v.z; p[3] = v.w;
    }
    a_lds[t]       = a[t];
    a_lds[t + 256] = a[t + 256];
    __syncthreads();   // the only barrier

    // ---- e-GEMM: e_k = (h*a_k) @ h^T ; wave w owns rows w*16..w*16+15 ----
    const int irow = w * 16 + (l & 15);
    f32x4 acc[4][4];   // [ct][k]
    #pragma unroll
    for (int ct = 0; ct < 4; ++ct)
        #pragma unroll
        for (int k = 0; k < 4; ++k)
            acc[ct][k] = (f32x4){0.f, 0.f, 0.f, 0.f};

    #pragma unroll
    for (int kk = 0; kk < 4; ++kk) {
        int d0 = kk * 32 + g8;
        bf16x8 hf = *(const bf16x8*)&h_lds[irow * HS + d0];
        float hff[8];
        #pragma unroll
        for (int e = 0; e < 8; ++e) hff[e] = (float)hf[e];
        bf16x8 hk[4];
        #pragma unroll
        for (int k = 0; k < 4; ++k) {
            float4 alo = *(const float4*)&a_lds[k * ND + d0];
            float4 ahi = *(const float4*)&a_lds[k * ND + d0 + 4];
            bf16x8 r;
            r[0] = (__bf16)(hff[0] * alo.x); r[1] = (__bf16)(hff[1] * alo.y);
            r[2] = (__bf16)(hff[2] * alo.z); r[3] = (__bf16)(hff[3] * alo.w);
            r[4] = (__bf16)(hff[4] * ahi.x); r[5] = (__bf16)(hff[5] * ahi.y);
            r[6] = (__bf16)(hff[6] * ahi.z); r[7] = (__bf16)(hff[7] * ahi.w);
            hk[k] = r;
        }
        bf16x8 bfr[4];
        #pragma unroll
        for (int ct = 0; ct < 4; ++ct)
            bfr[ct] = *(const bf16x8*)&h_lds[(ct * 16 + (l & 15)) * HS + d0];
        #pragma unroll
        for (int ct = 0; ct < 4; ++ct)
            #pragma unroll
            for (int k = 0; k < 4; ++k)
                acc[ct][k] = __builtin_amdgcn_mfma_f32_16x16x32_bf16(hk[k], bfr[ct], acc[ct][k], 0, 0, 0);
    }

    // ---- fused leakyrelu + adj-select (adj from LDS) ----
    float sel[4][4];   // [ct][r]
    #pragma unroll
    for (int ct = 0; ct < 4; ++ct)
        #pragma unroll
        for (int r = 0; r < 4; ++r) {
            int av = adj_lds[(i0 + r) * AJS + ct * 16 + (l & 15)];
            float e0 = fmaxf(acc[ct][0][r], 0.2f * acc[ct][0][r]);
            float e1 = fmaxf(acc[ct][1][r], 0.2f * acc[ct][1][r]);
            float e2 = fmaxf(acc[ct][2][r], 0.2f * acc[ct][2][r]);
            float e3 = fmaxf(acc[ct][3][r], 0.2f * acc[ct][3][r]);
            sel[ct][r] = av == 1 ? e0 : av == 2 ? e1 : av == 3 ? e2 : av == 4 ? e3 : -9.0e15f;
        }

    // ---- in-register softmax (row i0+r lives in this 16-lane group) ----
    #pragma unroll
    for (int r = 0; r < 4; ++r) {
        float m = fmaxf(fmaxf(sel[0][r], sel[1][r]), fmaxf(sel[2][r], sel[3][r]));
        m = fmaxf(m, __shfl_xor(m, 1));
        m = fmaxf(m, __shfl_xor(m, 2));
        m = fmaxf(m, __shfl_xor(m, 4));
        m = fmaxf(m, __shfl_xor(m, 8));
        float p0 = __expf(sel[0][r] - m);
        float p1 = __expf(sel[1][r] - m);
        float p2 = __expf(sel[2][r] - m);
        float p3 = __expf(sel[3][r] - m);
        float s = p0 + p1 + p2 + p3;
        s += __shfl_xor(s, 1);
        s += __shfl_xor(s, 2);
        s += __shfl_xor(s, 4);
        s += __shfl_xor(s, 8);
        float inv = 1.0f / s;
        int i = i0 + r;
        al_lds[i * AS +  0 + (l & 15)] = (__bf16)(p0 * inv);   // normalized alpha
        al_lds[i * AS + 16 + (l & 15)] = (__bf16)(p1 * inv);
        al_lds[i * AS + 32 + (l & 15)] = (__bf16)(p2 * inv);
        al_lds[i * AS + 48 + (l & 15)] = (__bf16)(p3 * inv);
    }

    // ---- PV transposed: out^T-tile = h^T @ alpha^T (A/B frag layouts identical
    //      -> operand swap), C col = i, rows = 4 consecutive d => float4 stores ----
    const int ia = w * 16 + (l & 15);
    bf16x8 pB0 = *(const bf16x8*)&al_lds[ia * AS + g8];        // k = j 0..31 slice
    bf16x8 pB1 = *(const bf16x8*)&al_lds[ia * AS + 32 + g8];   // k = j 32..63 slice
    float* outb = out + (size_t)b * NN * ND;
    unsigned trb = (unsigned)(unsigned long long)(&h_tr[0])
                 + (unsigned)(((l & 15) << 3) + (g << 8));
    #pragma unroll
    for (int dt = 0; dt < 8; ++dt) {
        unsigned ab = trb + dt * 2048;
        bf16x4 r0, r1, r2, r3;
        asm volatile("ds_read_b64_tr_b16 %0, %1"             : "=v"(r0) : "v"(ab));
        asm volatile("ds_read_b64_tr_b16 %0, %1 offset:128"  : "=v"(r1) : "v"(ab));
        asm volatile("ds_read_b64_tr_b16 %0, %1 offset:1024" : "=v"(r2) : "v"(ab));
        asm volatile("ds_read_b64_tr_b16 %0, %1 offset:1152" : "=v"(r3) : "v"(ab));
        asm volatile("s_waitcnt lgkmcnt(0)" ::: "memory");
        __builtin_amdgcn_sched_barrier(0);
        bf16x8 A0 = __builtin_shufflevector(r0, r1, 0, 1, 2, 3, 4, 5, 6, 7);
        bf16x8 A1 = __builtin_shufflevector(r2, r3, 0, 1, 2, 3, 4, 5, 6, 7);
        f32x4 o = {0.f, 0.f, 0.f, 0.f};
        o = __builtin_amdgcn_mfma_f32_16x16x32_bf16(A0, pB0, o, 0, 0, 0);
        o = __builtin_amdgcn_mfma_f32_16x16x32_bf16(A1, pB1, o, 0, 0, 0);
        float4 st = { o[0], o[1], o[2], o[3] };   // d = dt*16 + g*4 + 0..3, row i = ia
        *(float4*)&outb[ia * ND + dt * 16 + (g << 2)] = st;
    }
}

extern "C" void kernel_launch(void* const* d_in, const int* in_sizes, int n_in,
                              void* d_out, int out_size, void* d_ws, size_t ws_size,
                              hipStream_t stream) {
    const float* hidden = (const float*)d_in[0];
    const int*   adj    = (const int*)d_in[1];
    const float* a      = (const float*)d_in[2];
    float*       out    = (float*)d_out;
    gat_kernel<<<NB, 256, 0, stream>>>(hidden, adj, a, out);
}